// Round 1
// baseline (234.281 us; speedup 1.0000x reference)
//
#include <hip/hip_runtime.h>
#include <stdint.h>

// Greedy dedup = masked argmax scan. B=65536 rows, S=25 steps, V=25 vocab.
//
// R1: per-thread 4B gathers -> request-throughput bound. R2: global_load_lds
//   width=4 issues per-lane requests, no coalescing. R3: stage via
//   global_load_dword -> VGPR -> ds_write (known-good coalescer), 1-wave
//   blocks, 1-step prefetch. Measured 232.6us total, but top-5 rocprof rows
//   are all 640MB harness fills (~96us each) -> kernel itself is <95us,
//   modeled ~37us vs 28us roofline (177MB at 6.3TB/s).
// R4 (this): 2-step-deep register prefetch (pfE/pfO, loop unrolled x2 so all
//   pf indexing is compile-time -> stays in VGPRs, no scratch). Loads for
//   step s+2 are issued a full step (~900+cyc) before their vmcnt wait, so
//   no exposed HBM latency per step. In-flight/CU: 4 waves x 50 loads x 256B
//   = 51KB >> 9.2KB needed at 10.25 B/cyc/CU roofline.

#define S_LEN 25
#define VOCAB 25
#define ROWS 64                // rows per block == threads per block (1 wave)
#define SLICE (ROWS * VOCAB)   // 1600 dwords per step-slice
#define J_ITERS (SLICE / 64)   // 25 load slots per thread per step

__global__ __launch_bounds__(64) void greedy_dedup_kernel(
    const float* __restrict__ m, float* __restrict__ out, int B) {
  __shared__ float buf[2][SLICE];   // 2 x 6.4 KB input step-slices
  __shared__ float abuf[SLICE];     // 6.4 KB staged actions [row][s]
  __shared__ float vbuf[SLICE];     // 6.4 KB staged scores  [row][s]

  const int t = threadIdx.x;                       // 0..63, == lane
  const long long blk0 = (long long)blockIdx.x * ROWS;
  const float* base = m + blk0 * (S_LEN * VOCAB);  // block's contiguous region

  // Step-0 dword offsets for this thread's 25 staging slots. Slot q = j*64+t
  // covers the step-slice linearly; row = q/25, v = q%25. Lane-consecutive q
  // -> (mostly) consecutive global addresses -> full line coalescing.
  int off0[J_ITERS];
#pragma unroll
  for (int j = 0; j < J_ITERS; ++j) {
    int q = j * 64 + t;
    int row = q / VOCAB;
    int v = q - row * VOCAB;
    off0[j] = row * (S_LEN * VOCAB) + v;   // + s*25 per step
  }

  float pfE[J_ITERS], pfO[J_ITERS];   // two in-flight step slices (static idx)

  // Prologue: issue step 0 and step 1 (50 loads in flight), commit step 0.
#pragma unroll
  for (int j = 0; j < J_ITERS; ++j) pfE[j] = base[off0[j]];
#pragma unroll
  for (int j = 0; j < J_ITERS; ++j) pfO[j] = base[off0[j] + VOCAB];
#pragma unroll
  for (int j = 0; j < J_ITERS; ++j) buf[0][j * 64 + t] = pfE[j];  // waits pfE only
  __syncthreads();
  // Refill pfE with step 2 immediately: depth stays 2 steps.
#pragma unroll
  for (int j = 0; j < J_ITERS; ++j) pfE[j] = base[off0[j] + 2 * VOCAB];

  unsigned used = 0u;

  // Masked argmax over this row's 25 candidates (LDS stride 25 = odd ->
  // 2 lanes/bank = free). Ascending scan + strict '>' == jnp.argmax
  // first-max tie-breaking. best = original (unmasked) score (winner is
  // unmasked, so its masked value IS its original value).
  auto argmax_step = [&](const float* srcbuf, int s) {
    const float* src = srcbuf + t * VOCAB;
    float best = -3.402823466e38f;
    int bi = 0;
#pragma unroll
    for (int v = 0; v < VOCAB; ++v) {
      float x = src[v];
      bool free_v = ((used >> v) & 1u) == 0u;
      if (free_v && x > best) { best = x; bi = v; }
    }
    used |= (1u << bi);
    abuf[t * VOCAB + s] = (float)bi;   // exact small int in fp32
    vbuf[t * VOCAB + s] = best;
  };

  // Invariant at loop top (s even): buf[0]=step s, pfO=step s+1 (issued),
  // pfE=step s+2 (issued). Unrolled x2 so pfE/pfO roles are compile-time.
  for (int s = 0; s < S_LEN - 2; s += 2) {
    // --- even half: step s ---
    argmax_step(buf[0], s);
#pragma unroll
    for (int j = 0; j < J_ITERS; ++j) buf[1][j * 64 + t] = pfO[j];  // step s+1
    if (s + 3 < S_LEN) {
      const int soff = (s + 3) * VOCAB;
#pragma unroll
      for (int j = 0; j < J_ITERS; ++j) pfO[j] = base[off0[j] + soff];
    }
    __syncthreads();

    // --- odd half: step s+1 ---
    argmax_step(buf[1], s + 1);
#pragma unroll
    for (int j = 0; j < J_ITERS; ++j) buf[0][j * 64 + t] = pfE[j];  // step s+2
    if (s + 4 < S_LEN) {
      const int soff = (s + 4) * VOCAB;
#pragma unroll
      for (int j = 0; j < J_ITERS; ++j) pfE[j] = base[off0[j] + soff];
    }
    __syncthreads();
  }
  // Epilogue: step 24 sits in buf[0] (S_LEN odd).
  argmax_step(buf[0], S_LEN - 1);
  __syncthreads();

  // Coalesced copy-out: block's act/val chunks are contiguous 1600-dword
  // regions and the LDS [row][s] layout matches global linear order.
  float* gact = out + blk0 * S_LEN;
  float* gval = out + (long long)B * S_LEN + blk0 * S_LEN;
#pragma unroll
  for (int k = 0; k < J_ITERS; ++k) {
    int idx = k * 64 + t;
    gact[idx] = abuf[idx];
    gval[idx] = vbuf[idx];
  }
}

extern "C" void kernel_launch(void* const* d_in, const int* in_sizes, int n_in,
                              void* d_out, int out_size, void* d_ws, size_t ws_size,
                              hipStream_t stream) {
  const float* m = (const float*)d_in[0];
  float* out = (float*)d_out;
  int B = in_sizes[0] / (S_LEN * VOCAB);   // 65536
  int grid = B / ROWS;                     // 1024 one-wave blocks, 4/CU
  greedy_dedup_kernel<<<grid, ROWS, 0, stream>>>(m, out, B);
}